// Round 7
// baseline (311.812 us; speedup 1.0000x reference)
//
#include <hip/hip_runtime.h>

using ull = unsigned long long;

typedef float f32x4v __attribute__((ext_vector_type(4)));

// Explicit global load: volatile asm -> issues in program order, result is an
// asm output so no IR pass can sink or duplicate it.
__device__ __forceinline__ f32x4v gld(const float4* p) {
    f32x4v d;
    asm volatile("global_load_dwordx4 %0, %1, off" : "=v"(d) : "v"(p));
    return d;
}

// ---------------- problem constants ----------------
constexpr int NB  = 32;
constexpr int HW0 = 320 * 320;
constexpr int HW1 = 160 * 160;
constexpr int N0  = NB * HW0;            // 3,276,800
constexpr int N1  = NB * HW1;            // 819,200
constexpr int HW0_4 = HW0 / 4;
constexpr int HW1_4 = HW1 / 4;
constexpr int BLK = 256;

// score blocks: 4 uint4-packs (16 px) per thread -> 1024 packs per block
constexpr int SB0 = N0 / 4 / 1024;       // 800
constexpr int SB1 = N1 / 4 / 1024;       // 200
constexpr int SBT = SB0 + SB1;           // 1000
// bbox blocks: 5 float4 per stream per thread, fully unrolled
constexpr int BBLK0 = 2560, BBLK1 = 640; // 3,276,800/(2560*256)=5 ; 819,200/(640*256)=5
constexpr int P1_GRID = SBT + BBLK0 + BBLK1;   // 4200
// refine: 4 uint4-packs (16 px) per thread
constexpr int RB0 = 800, RB1 = 200, GRID_R = RB0 + RB1;
constexpr int RT0 = RB0 * BLK;           // 204,800 (uint4 stride)
constexpr int RT1 = RB1 * BLK;           // 51,200

constexpr float CE_SCALE = 16384.0f;
constexpr ull MASK40 = (1ull << 40) - 1;
constexpr int REP1 = 32, REP2 = 8;

// ---------------- workspace layout (bytes) ----------------
constexpr size_t CTRL_OFF = 0;                                   // (reserved)
constexpr size_t ACC_OFF  = 256;                                 // Acc[2] (within zeroed page)
constexpr size_t H1_OFF  = 4096;                                 // u32 [2][1024][REP1] (bin-major)
constexpr size_t H2_OFF  = H1_OFF + (size_t)2 * 1024 * REP1 * 4; // u32 [2][2048][REP2]
constexpr size_t H3_OFF  = H2_OFF + (size_t)2 * 2048 * REP2 * 4; // u64 [2][1024][REP2]
constexpr size_t FIN_OFF = H3_OFF + (size_t)2 * 1024 * REP2 * 8; // [2][REP2][2] u64 cnt, double ce
constexpr size_t ZERO_END = FIN_OFF + 2 * REP2 * 16;             // 528,640
constexpr int    ZERO_V4  = (int)(ZERO_END / 16);                // 33,040 uint4s
constexpr size_t PN_OFF  = ZERO_END;                             // u32[SBT]
constexpr size_t CEP_OFF = PN_OFF + SBT * 4;                     // double2[SBT] (ce0, ce1nn)
constexpr size_t DM_OFF  = CEP_OFF + (size_t)SBT * 16;           // double2[3200] (d2, ms)
// compact reduction outputs (written-before-read each launch; no zeroing needed)
constexpr size_t CN1_OFF = DM_OFF + (size_t)3200 * 16;           // u32[2][1024]
constexpr size_t CN2_OFF = CN1_OFF + (size_t)2 * 1024 * 4;       // u32[2][2048]
constexpr size_t CEV_OFF = CN2_OFF + (size_t)2 * 2048 * 4;       // u64[2][1024] (reserved)
constexpr size_t PB_OFF  = ((CEV_OFF + (size_t)2 * 1024 * 8 + 255) / 256) * 256;
constexpr size_t WS_NEED = PB_OFF + (size_t)(N0 + N1) * 4;       // ~17.05 MB

struct Acc { ull pn; double ce0, ce1, d2, ms; };

__device__ inline Acc*      acc_of(void* ws)       { return (Acc*)((char*)ws + ACC_OFF); }
__device__ inline unsigned* h1_of(void* ws, int br) { return (unsigned*)((char*)ws + H1_OFF) + (size_t)br * 1024 * REP1; }
__device__ inline unsigned* h2_of(void* ws, int br) { return (unsigned*)((char*)ws + H2_OFF) + (size_t)br * 2048 * REP2; }
__device__ inline ull*      h3_of(void* ws, int br) { return (ull*)((char*)ws + H3_OFF) + (size_t)br * 1024 * REP2; }
__device__ inline ull*      fin_of(void* ws, int br) { return (ull*)((char*)ws + FIN_OFF) + (size_t)br * REP2 * 2; }
__device__ inline unsigned* pn_part(void* ws)  { return (unsigned*)((char*)ws + PN_OFF); }
__device__ inline double2*  cep_part(void* ws) { return (double2*)((char*)ws + CEP_OFF); }
__device__ inline double2*  dm_part(void* ws)  { return (double2*)((char*)ws + DM_OFF); }
__device__ inline unsigned* cnt1_of(void* ws)  { return (unsigned*)((char*)ws + CN1_OFF); }
__device__ inline unsigned* cnt2_of(void* ws)  { return (unsigned*)((char*)ws + CN2_OFF); }
__device__ inline unsigned* pb_of(void* ws, int br) { return (unsigned*)((char*)ws + PB_OFF) + (br ? (size_t)N0 : 0); }

// ---------------- reduce helpers ----------------
__device__ __forceinline__ unsigned wred_u(unsigned v) {
#pragma unroll
    for (int o = 32; o > 0; o >>= 1) v += __shfl_down(v, o, 64);
    return v;
}
__device__ __forceinline__ ull wred_q(ull v) {
#pragma unroll
    for (int o = 32; o > 0; o >>= 1) v += __shfl_down(v, o, 64);
    return v;
}
__device__ __forceinline__ double wred_d(double v) {
#pragma unroll
    for (int o = 32; o > 0; o >>= 1) v += __shfl_down(v, o, 64);
    return v;
}

// ---------------- kernels ----------------
__global__ __launch_bounds__(256) void zero_ws_k(uint4* p, int n) {
    int i = blockIdx.x * BLK + threadIdx.x;
    if (i < n) p[i] = make_uint4(0, 0, 0, 0);
}

// ---- pass1: asm-forced 16-deep load burst; latency hidden under h-zero+barrier ----
template <int BR, bool STORED>
__device__ void score_body(const float4* __restrict__ score, const float4* __restrict__ glabel,
                           void* ws, int blk, int gblk, unsigned* h)
{
    constexpr int HW4 = BR ? HW1_4 : HW0_4;
    const int t = threadIdx.x;
    const int base = blk * 1024 + t;

    f32x4v s0[4], s1[4], g0[4], g1[4];
    int idx[4];
#pragma unroll
    for (int u = 0; u < 4; u++) {
        idx[u] = base + 256 * u;
        int b = idx[u] / HW4, r = idx[u] - b * HW4;
        const float4* sp = score  + (size_t)(b * 2) * HW4 + r;
        const float4* gp = glabel + (size_t)(b * 6) * HW4 + r;
        s0[u] = gld(sp);  s1[u] = gld(sp + HW4);
        g0[u] = gld(gp);  g1[u] = gld(gp + HW4);
    }

    // overlap load latency with LDS hist zeroing + barrier
    for (int i = t; i < 1024; i += BLK) h[i] = 0;
    __syncthreads();

    // single drain point; all 16 result vectors are operands -> all live here,
    // consumers data-depend on this asm (cannot be hoisted above it).
    asm volatile("s_waitcnt vmcnt(0)"
        : "+v"(s0[0]), "+v"(s0[1]), "+v"(s0[2]), "+v"(s0[3]),
          "+v"(s1[0]), "+v"(s1[1]), "+v"(s1[2]), "+v"(s1[3]),
          "+v"(g0[0]), "+v"(g0[1]), "+v"(g0[2]), "+v"(g0[3]),
          "+v"(g1[0]), "+v"(g1[1]), "+v"(g1[2]), "+v"(g1[3]));

    unsigned posc = 0, negc = 0;
    double ce0d = 0.0, ce1d = 0.0;
#pragma unroll
    for (int u = 0; u < 4; u++) {
        uint4 pk;
        unsigned bins[4];
        float c0 = 0.0f, c1 = 0.0f;
#pragma unroll
        for (int j = 0; j < 4; j++) {
            float a = s0[u][j], cc = s1[u][j];
            float m = fmaxf(a, cc);
            float e0 = __expf(a - m), e1 = __expf(cc - m);
            float inv = 1.0f / (e0 + e1);
            float p0 = e0 * inv, p1 = e1 * inv;
            float l0 = g0[u][j], l1 = g1[u][j];
            bool pos = l0 > 0.5f, neg = l1 > 0.5f;
            posc += pos ? 1u : 0u;
            negc += neg ? 1u : 0u;
            if (pos)  c0 += -l0 * __logf(p0);
            if (!neg) c1 += -l1 * __logf(p1);
            unsigned pb = __float_as_uint(p1);
            (&pk.x)[j] = pb | (neg ? 0x80000000u : 0u);
            bins[j] = (neg ? 0u : 512u) + (pb >> 21);
        }
        ce0d += (double)c0; ce1d += (double)c1;
        if (STORED) ((uint4*)pb_of(ws, BR))[idx[u]] = pk;
#pragma unroll
        for (int j = 0; j < 4; j++) {
            unsigned bj = bins[j];
            if (bj != 0xFFFFFFFFu) {
                unsigned cnt = 1;
#pragma unroll
                for (int k = j + 1; k < 4; k++)
                    if (bins[k] == bj) { cnt++; bins[k] = 0xFFFFFFFFu; }
                atomicAdd(&h[bj], cnt);
            }
        }
    }

    unsigned pn = posc | (negc << 16);
    pn = wred_u(pn);
    double C0 = wred_d(ce0d);
    double C1 = wred_d(ce1d);
    __shared__ unsigned spn[4];
    __shared__ double sc0[4], sc1[4];
    int w = t >> 6, lane = t & 63;
    if (lane == 0) { spn[w] = pn; sc0[w] = C0; sc1[w] = C1; }
    __syncthreads();   // also orders LDS hist atomics before flush
    if (t == 0) {
        pn_part(ws)[gblk] = spn[0] + spn[1] + spn[2] + spn[3];
        cep_part(ws)[gblk] = make_double2(sc0[0] + sc0[1] + sc0[2] + sc0[3],
                                          sc1[0] + sc1[1] + sc1[2] + sc1[3]);
    }
    const int rep = gblk & (REP1 - 1);
    unsigned* H = h1_of(ws, BR);
    for (int i = t; i < 1024; i += BLK) {
        unsigned v = h[i];
        if (v) atomicAdd(&H[(size_t)i * REP1 + rep], v);
    }
}

template <int BR>
__device__ void bbox_body(const float4* __restrict__ bbox, const float4* __restrict__ gmask,
                          const float4* __restrict__ glabel, void* ws, int blk, int gblk)
{
    constexpr int HW4 = BR ? HW1_4 : HW0_4;
    constexpr int NT  = (BR ? BBLK1 : BBLK0) * BLK;
    const int t = threadIdx.x;
    const int i0 = blk * BLK + t;

    f32x4v pb4[5], gm[5], gl[5];
#pragma unroll
    for (int k = 0; k < 5; k++) {
        int i = i0 + k * NT;
        int b = i / (4 * HW4);
        int off = i + (2 * b + 2) * HW4;
        pb4[k] = gld(bbox + i);
        gm[k]  = gld(gmask + off);
        gl[k]  = gld(glabel + off);
    }
    asm volatile("s_waitcnt vmcnt(0)"
        : "+v"(pb4[0]), "+v"(pb4[1]), "+v"(pb4[2]), "+v"(pb4[3]), "+v"(pb4[4]),
          "+v"(gm[0]),  "+v"(gm[1]),  "+v"(gm[2]),  "+v"(gm[3]),  "+v"(gm[4]),
          "+v"(gl[0]),  "+v"(gl[1]),  "+v"(gl[2]),  "+v"(gl[3]),  "+v"(gl[4]));

    float d2 = 0.0f, ms = 0.0f;
#pragma unroll
    for (int k = 0; k < 5; k++) {
#pragma unroll
        for (int j = 0; j < 4; j++) {
            float m = gm[k][j];
            float d = (pb4[k][j] - gl[k][j]) * m;
            d2 += d * d;
            ms += m;
        }
    }
    double D = wred_d((double)d2);
    double M = wred_d((double)ms);
    __shared__ double sdd[4], sdm[4];
    int w = t >> 6, lane = t & 63;
    if (lane == 0) { sdd[w] = D; sdm[w] = M; }
    __syncthreads();
    if (t == 0)
        dm_part(ws)[gblk] = make_double2(sdd[0] + sdd[1] + sdd[2] + sdd[3],
                                         sdm[0] + sdm[1] + sdm[2] + sdm[3]);
}

template <bool STORED>
__global__ __launch_bounds__(256) void pass1(
    const float4* __restrict__ sc0, const float4* __restrict__ bb0,
    const float4* __restrict__ mk0, const float4* __restrict__ lb0,
    const float4* __restrict__ sc1, const float4* __restrict__ bb1,
    const float4* __restrict__ mk1, const float4* __restrict__ lb1,
    void* ws)
{
    __shared__ unsigned h[1024];
    const int bid = blockIdx.x;
    if (bid < SBT) {
        if (bid < SB0) score_body<0, STORED>(sc0, lb0, ws, bid, bid, h);
        else           score_body<1, STORED>(sc1, lb1, ws, bid - SB0, bid, h);
    } else if (bid < SBT + BBLK0) {
        bbox_body<0>(bb0, mk0, lb0, ws, bid - SBT, bid - SBT);
    } else {
        bbox_body<1>(bb1, mk1, lb1, ws, bid - SBT - BBLK0, bid - SBT);
    }
}

// ---------------- redundant per-block selects ----------------
// All inputs (PN, h1, h2, cnt1, cnt2, Acc.pn) are finalized integers at the
// preceding kernel boundary, so every block computes the SAME result.

struct Sel1R { unsigned P, negn, haspos, sel1, tnext, done, hA0; };

// shared scratch: pref[256], shv[4], shq[4]
__device__ void sel1_common(int br, unsigned P, unsigned negn, const unsigned* C1raw,
                            bool rawRep, Sel1R& R, unsigned* pref, unsigned* shv)
{
    const int t = threadIdx.x;
    const unsigned N = br ? N1 : N0;
    const unsigned haspos = (P > 0) ? 1u : 0u;
    unsigned k = haspos ? ((5u * P < negn) ? 5u * P : negn) : (N / 10u);
    unsigned target = (k < 1u) ? 1u : k;
    if (target > N) target = N;

    unsigned cnt[2], ssum = 0;
#pragma unroll
    for (int j = 0; j < 2; j++) {
        int i = t * 2 + j;
        unsigned s;
        if (rawRep) {
            const uint4* p = (const uint4*)(C1raw + (size_t)i * REP1);
            s = 0;
#pragma unroll
            for (int r = 0; r < REP1 / 4; r++) { uint4 q = p[r]; s += q.x + q.y + q.z + q.w; }
        } else {
            s = C1raw[i];
        }
        if (i == 0) shv[2] = s;
        if (!haspos) {
            if (rawRep) {
                const uint4* p2 = (const uint4*)(C1raw + (size_t)(512 + i) * REP1);
#pragma unroll
                for (int r = 0; r < REP1 / 4; r++) { uint4 q = p2[r]; s += q.x + q.y + q.z + q.w; }
            } else {
                s += C1raw[512 + i];
            }
        }
        unsigned cv = s + ((haspos && i == 0) ? (N - negn) : 0u);
        cnt[j] = cv; ssum += cv;
    }
    if (t == 0) { shv[0] = 0; shv[1] = 1; }
    __syncthreads();
    pref[t] = ssum;
    __syncthreads();
    for (int off = 1; off < 256; off <<= 1) {
        unsigned x = (t >= off) ? pref[t - off] : 0u;
        __syncthreads();
        pref[t] += x;
        __syncthreads();
    }
    unsigned tot = pref[255];
    if (target > tot) target = tot;
    unsigned before = pref[t] - ssum;
#pragma unroll
    for (int j = 0; j < 2; j++) {
        if (tot && before < target && before + cnt[j] >= target) {
            shv[0] = (unsigned)(t * 2 + j);
            shv[1] = target - before;
        }
        before += cnt[j];
    }
    __syncthreads();
    R.P = P; R.negn = negn; R.haspos = haspos;
    R.sel1 = shv[0]; R.tnext = shv[1]; R.hA0 = shv[2];
    R.done = (haspos && R.sel1 == 0 && R.hA0 == 0) ? 1u : 0u;
    __syncthreads();   // protect shv/pref reuse by caller
}

// version used by refine2': raw PN + raw h1
__device__ void compute_sel1_raw(void* ws, int br, Sel1R& R,
                                 unsigned* pref, unsigned* shv, ull* shq)
{
    const int t = threadIdx.x;
    const unsigned* PN = pn_part(ws);
    const int lo = br ? SB0 : 0, hi = br ? SBT : SB0;
    ull pn = 0;
    for (int i = lo + t; i < hi; i += BLK) {
        unsigned v = PN[i];
        pn += (ull)(v & 0xFFFFu) | ((ull)(v >> 16) << 32);
    }
    pn = wred_q(pn);
    int w = t >> 6;
    if ((t & 63) == 0) shq[w] = pn;
    __syncthreads();
    ull tot = shq[0] + shq[1] + shq[2] + shq[3];
    unsigned P = (unsigned)(tot & 0xFFFFFFFFull);
    unsigned negn = (unsigned)(tot >> 32);
    __syncthreads();
    sel1_common(br, P, negn, h1_of(ws, br), true, R, pref, shv);
}

// version used by refine3'/scan_final: Acc.pn + compact cnt1
__device__ void compute_sel1_compact(void* ws, int br, Sel1R& R,
                                     unsigned* pref, unsigned* shv)
{
    ull pn = acc_of(ws)[br].pn;
    unsigned P = (unsigned)(pn & 0xFFFFFFFFull);
    unsigned negn = (unsigned)(pn >> 32);
    sel1_common(br, P, negn, cnt1_of(ws) + (size_t)br * 1024, false, R, pref, shv);
}

// level-2 select; C2raw either raw h2 (rep-major, rawRep) or compact cnt2
__device__ void compute_sel2(const unsigned* C2raw, bool rawRep, unsigned target,
                             unsigned& sel2, unsigned& tnext, unsigned* pref, unsigned* shv)
{
    const int t = threadIdx.x;
    unsigned cnt[8], ssum = 0;
#pragma unroll
    for (int j = 0; j < 8; j++) {
        int i = t * 8 + j;
        unsigned s;
        if (rawRep) {
            const uint4* p = (const uint4*)(C2raw + (size_t)i * REP2);
            uint4 q0 = p[0], q1 = p[1];
            s = q0.x + q0.y + q0.z + q0.w + q1.x + q1.y + q1.z + q1.w;
        } else {
            s = C2raw[i];
        }
        cnt[j] = s; ssum += s;
    }
    if (t == 0) { shv[0] = 0; shv[1] = 1; }
    __syncthreads();
    pref[t] = ssum;
    __syncthreads();
    for (int off = 1; off < 256; off <<= 1) {
        unsigned x = (t >= off) ? pref[t - off] : 0u;
        __syncthreads();
        pref[t] += x;
        __syncthreads();
    }
    unsigned tot = pref[255];
    if (target > tot) target = tot;
    unsigned before = pref[t] - ssum;
#pragma unroll
    for (int j = 0; j < 8; j++) {
        if (tot && before < target && before + cnt[j] >= target) {
            shv[0] = (unsigned)(t * 8 + j);
            shv[1] = target - before;
        }
        before += cnt[j];
    }
    __syncthreads();
    sel2 = shv[0]; tnext = shv[1];
    __syncthreads();
}

// ---- refine2 body (ctrl reads replaced by params) ----
template <int BR, bool STORED>
__device__ void refine2_body(const float4* __restrict__ score, const float4* __restrict__ glabel,
                             void* ws, int blk, unsigned* h, unsigned haspos, unsigned sel1)
{
    constexpr int T = BR ? RT1 : RT0;
    constexpr int HW4 = BR ? HW1_4 : HW0_4;
    const int base = blk * BLK + (int)threadIdx.x;

    unsigned pk[16];
    if (STORED) {
        const uint4* pb4 = (const uint4*)pb_of(ws, BR);
#pragma unroll
        for (int i = 0; i < 4; i++) {
            uint4 q = pb4[base + i * T];
            pk[i*4+0]=q.x; pk[i*4+1]=q.y; pk[i*4+2]=q.z; pk[i*4+3]=q.w;
        }
    } else {
#pragma unroll
        for (int i = 0; i < 4; i++) {
            int id = base + i * T;
            int b = id / HW4, r = id - b * HW4;
            float4 s0 = score[(size_t)(b*2)*HW4 + r];
            float4 s1 = score[(size_t)(b*2+1)*HW4 + r];
            float4 g1 = glabel[(size_t)(b*6+1)*HW4 + r];
#pragma unroll
            for (int j = 0; j < 4; j++) {
                float a=(&s0.x)[j], cc=(&s1.x)[j];
                float m=fmaxf(a,cc);
                float e0=__expf(a-m), e1=__expf(cc-m);
                float p1=e1/(e0+e1);
                pk[i*4+j] = __float_as_uint(p1) | (((&g1.x)[j] > 0.5f) ? 0x80000000u : 0u);
            }
        }
    }
    unsigned z = 0;
#pragma unroll
    for (int i = 0; i < 4; i++) {
        unsigned bins[4];
#pragma unroll
        for (int j = 0; j < 4; j++) {
            unsigned raw = pk[i*4+j], pbv = raw & 0x7FFFFFFFu;
            unsigned npb = haspos ? ((raw >> 31) ? pbv : 0u) : pbv;
            bool m = (npb >> 21) == sel1;
            if (m && npb == 0) { z++; bins[j] = 0xFFFFFFFFu; }
            else bins[j] = m ? ((npb >> 10) & 0x7FFu) : 0xFFFFFFFFu;
        }
#pragma unroll
        for (int j = 0; j < 4; j++) {
            unsigned bj = bins[j];
            if (bj != 0xFFFFFFFFu) {
                unsigned cnt = 1;
#pragma unroll
                for (int k = j + 1; k < 4; k++)
                    if (bins[k] == bj) { cnt++; bins[k] = 0xFFFFFFFFu; }
                atomicAdd(&h[bj], cnt);
            }
        }
    }
    if (z) atomicAdd(&h[0], z);
}

// ---- refine3 body (ctrl reads replaced by params) ----
template <int BR, bool STORED>
__device__ void refine3_body(const float4* __restrict__ score, const float4* __restrict__ glabel,
                             void* ws, int blk, int gblk, ull* h,
                             unsigned haspos, unsigned sel1, unsigned sel2)
{
    const unsigned sel12 = (sel1 << 11) | sel2;
    constexpr int T = BR ? RT1 : RT0;
    constexpr int HW4 = BR ? HW1_4 : HW0_4;
    constexpr int HW  = BR ? HW1 : HW0;
    const int base = blk * BLK + (int)threadIdx.x;
    const float* glab_s = (const float*)glabel;

    unsigned pk[16];
    float g1v[16];
    if (STORED) {
        const uint4* pb4 = (const uint4*)pb_of(ws, BR);
#pragma unroll
        for (int i = 0; i < 4; i++) {
            uint4 q = pb4[base + i * T];
            pk[i*4+0]=q.x; pk[i*4+1]=q.y; pk[i*4+2]=q.z; pk[i*4+3]=q.w;
        }
    } else {
#pragma unroll
        for (int i = 0; i < 4; i++) {
            int id = base + i * T;
            int b = id / HW4, r = id - b * HW4;
            float4 s0 = score[(size_t)(b*2)*HW4 + r];
            float4 s1 = score[(size_t)(b*2+1)*HW4 + r];
            float4 g1 = glabel[(size_t)(b*6+1)*HW4 + r];
#pragma unroll
            for (int j = 0; j < 4; j++) {
                float a=(&s0.x)[j], cc=(&s1.x)[j];
                float m=fmaxf(a,cc);
                float e0=__expf(a-m), e1=__expf(cc-m);
                float p1=e1/(e0+e1);
                pk[i*4+j] = __float_as_uint(p1) | (((&g1.x)[j] > 0.5f) ? 0x80000000u : 0u);
                g1v[i*4+j] = (&g1.x)[j];
            }
        }
    }

    ull cnt_lt = 0;
    double ce_lt = 0.0;
    ull zpack = 0;
#pragma unroll
    for (int i = 0; i < 4; i++) {
#pragma unroll
        for (int j = 0; j < 4; j++) {
            unsigned raw = pk[i*4+j], pbv = raw & 0x7FFFFFFFu;
            unsigned npb = haspos ? ((raw >> 31) ? pbv : 0u) : pbv;
            bool iszero = (npb == 0);
            if (iszero && sel12 != 0) continue;  // accounted via base in scan_final
            unsigned b1 = npb >> 21, b2 = (npb >> 10) & 0x7FFu;
            bool lt = (b1 < sel1) || (b1 == sel1 && b2 < sel2);
            bool eq = ((npb >> 10) == sel12);
            if (lt || eq) {
                float g1s;
                if (STORED) {
                    int px = (base + i * T) * 4 + j;
                    int bb = px / HW, rr = px - bb * HW;
                    g1s = glab_s[(size_t)(bb * 6 + 1) * HW + rr];
                } else {
                    g1s = g1v[i*4+j];
                }
                float ce = -g1s * __logf(__uint_as_float(pbv));
                if (lt) { cnt_lt++; ce_lt += (double)ce; }
                else {
                    ull v = (1ull << 40) | (ull)__float2uint_rn(ce * CE_SCALE);
                    if (iszero) zpack += v;
                    else atomicAdd(&h[npb & 0x3FFu], v);
                }
            }
        }
    }
    if (zpack) atomicAdd(&h[0], zpack);

    ull CL = wred_q(cnt_lt);
    double CE = wred_d(ce_lt);
    __shared__ ull sq[4];
    __shared__ double sd[4];
    int t = threadIdx.x, w = t >> 6, lane = t & 63;
    if (lane == 0) { sq[w] = CL; sd[w] = CE; }
    __syncthreads();   // also orders LDS hist atomics before flush
    if (t == 0) {
        ull totc = sq[0] + sq[1] + sq[2] + sq[3];
        double totd = sd[0] + sd[1] + sd[2] + sd[3];
        ull* F = fin_of(ws, BR) + (size_t)(gblk & (REP2 - 1)) * 2;
        if (totc) atomicAdd(&F[0], totc);
        if (totd != 0.0) atomicAdd((double*)&F[1], totd);
    }
    const int rep = gblk & (REP2 - 1);
    ull* H = h3_of(ws, BR);
    for (int i = t; i < 1024; i += BLK) {
        ull v = h[i];
        if (v) atomicAdd(&H[(size_t)i * REP2 + rep], v);
    }
}

// ---- refine2': spare compaction duties + per-block select1 + tile work ----
template <bool STORED>
__global__ __launch_bounds__(256) void refine2_k2(
    const float4* __restrict__ sc0, const float4* __restrict__ lb0,
    const float4* __restrict__ sc1, const float4* __restrict__ lb1, void* ws)
{
    __shared__ unsigned h[2048];
    __shared__ unsigned pref[256];
    __shared__ unsigned shv[4];
    __shared__ ull shq[4];
    const int t = threadIdx.x;
    const int bid = blockIdx.x;

    // spare duties: compact h1 -> cnt1; reduce PN/CEP -> Acc; reduce DM -> Acc.
    if (bid < 8) {
        const int job = bid * BLK + t;            // 0..2047
        const int jbr = job >> 10, bin = job & 1023;
        const uint4* p = (const uint4*)(h1_of(ws, jbr) + (size_t)bin * REP1);
        unsigned s = 0;
#pragma unroll
        for (int r = 0; r < REP1 / 4; r++) { uint4 q = p[r]; s += q.x + q.y + q.z + q.w; }
        cnt1_of(ws)[job] = s;
    } else if (bid < 16) {
        const int i = (bid - 8) * BLK + t;        // 0..2047, valid < SBT
        ull pv = 0; double a = 0.0, b = 0.0; bool hi = false;
        if (i < SBT) {
            unsigned v = pn_part(ws)[i];
            double2 ce = cep_part(ws)[i];
            pv = (ull)(v & 0xFFFFu) | ((ull)(v >> 16) << 32);
            a = ce.x; b = ce.y; hi = (i >= SB0);
        }
        ull p0 = hi ? 0 : pv, p1 = hi ? pv : 0;
        double a0 = hi ? 0.0 : a, a1 = hi ? a : 0.0;
        double b0 = hi ? 0.0 : b, b1 = hi ? b : 0.0;
        p0 = wred_q(p0); p1 = wred_q(p1);
        a0 = wred_d(a0); a1 = wred_d(a1); b0 = wred_d(b0); b1 = wred_d(b1);
        if ((t & 63) == 0) {
            Acc* A = acc_of(ws);
            if (p0) atomicAdd(&A[0].pn, p0);
            if (p1) atomicAdd(&A[1].pn, p1);
            if (a0 != 0.0) atomicAdd(&A[0].ce0, a0);
            if (a1 != 0.0) atomicAdd(&A[1].ce0, a1);
            if (b0 != 0.0) atomicAdd(&A[0].ce1, b0);
            if (b1 != 0.0) atomicAdd(&A[1].ce1, b1);
        }
    } else if (bid < 32) {
        const int i = (bid - 16) * BLK + t;       // 0..4095, valid < 3200
        double d = 0.0, m = 0.0; bool hi = false;
        if (i < BBLK0 + BBLK1) {
            double2 v = dm_part(ws)[i];
            d = v.x; m = v.y; hi = (i >= BBLK0);
        }
        double d0 = hi ? 0.0 : d, d1 = hi ? d : 0.0;
        double m0 = hi ? 0.0 : m, m1 = hi ? m : 0.0;
        d0 = wred_d(d0); d1 = wred_d(d1); m0 = wred_d(m0); m1 = wred_d(m1);
        if ((t & 63) == 0) {
            Acc* A = acc_of(ws);
            if (d0 != 0.0) atomicAdd(&A[0].d2, d0);
            if (d1 != 0.0) atomicAdd(&A[1].d2, d1);
            if (m0 != 0.0) atomicAdd(&A[0].ms, m0);
            if (m1 != 0.0) atomicAdd(&A[1].ms, m1);
        }
    }

    const int br  = (bid < RB0) ? 0 : 1;
    const int blk = (bid < RB0) ? bid : bid - RB0;

    Sel1R s1;
    compute_sel1_raw(ws, br, s1, pref, shv, shq);
    if (s1.done) return;

    for (int i = t; i < 2048; i += BLK) h[i] = 0;
    __syncthreads();
    if (br == 0) refine2_body<0, STORED>(sc0, lb0, ws, blk, h, s1.haspos, s1.sel1);
    else         refine2_body<1, STORED>(sc1, lb1, ws, blk, h, s1.haspos, s1.sel1);
    __syncthreads();
    const int rep = bid & (REP2 - 1);
    unsigned* H = h2_of(ws, br);
    for (int i = t; i < 2048; i += BLK) {
        unsigned v = h[i];
        if (v) atomicAdd(&H[(size_t)i * REP2 + rep], v);
    }
}

// ---- refine3': spare h2 compaction + per-block select1 (compact) + select2 (raw h2) + tile ----
template <bool STORED>
__global__ __launch_bounds__(256) void refine3_k2(
    const float4* __restrict__ sc0, const float4* __restrict__ lb0,
    const float4* __restrict__ sc1, const float4* __restrict__ lb1, void* ws)
{
    __shared__ ull h[1024];
    __shared__ unsigned pref[256];
    __shared__ unsigned shv[4];
    const int t = threadIdx.x;
    const int bid = blockIdx.x;

    // spare duty: compact h2 -> cnt2 (for scan_final)
    if (bid < 16) {
        const int job = bid * BLK + t;            // 0..4095
        const int jbr = job >> 11, bin = job & 2047;
        const uint4* p = (const uint4*)(h2_of(ws, jbr) + (size_t)bin * REP2);
        uint4 q0 = p[0], q1 = p[1];
        cnt2_of(ws)[job] = q0.x + q0.y + q0.z + q0.w + q1.x + q1.y + q1.z + q1.w;
    }

    const int br  = (bid < RB0) ? 0 : 1;
    const int blk = (bid < RB0) ? bid : bid - RB0;

    Sel1R s1;
    compute_sel1_compact(ws, br, s1, pref, shv);
    if (s1.done) return;

    unsigned sel2, tnx2;
    compute_sel2(h2_of(ws, br), true, s1.tnext, sel2, tnx2, pref, shv);

    for (int i = t; i < 1024; i += BLK) h[i] = 0;
    __syncthreads();
    if (br == 0) refine3_body<0, STORED>(sc0, lb0, ws, blk, bid, h, s1.haspos, s1.sel1, sel2);
    else         refine3_body<1, STORED>(sc1, lb1, ws, blk, bid, h, s1.haspos, s1.sel1, sel2);
}

// ---- scan_final: single small block on compact data + h3/fin ----
__global__ __launch_bounds__(256) void scan_final(void* ws, float* out)
{
    const int t = threadIdx.x;
    __shared__ unsigned pref[256];
    __shared__ unsigned shv[4];
    __shared__ ull qscr[4];
    __shared__ double sls[2], slb[2];

    for (int br = 0; br < 2; br++) {
        const unsigned N = br ? N1 : N0;
        Acc* A = acc_of(ws) + br;
        ull pn = A->pn;
        unsigned P = (unsigned)(pn & 0xFFFFFFFFull);
        unsigned negn = (unsigned)(pn >> 32);
        double CE0 = A->ce0, CE1NN = A->ce1;
        double D = A->d2, M = A->ms;
        double lb = (M > 0.0) ? D / fmax(M, 1e-8) : 0.0;

        Sel1R s1;
        compute_sel1_compact(ws, br, s1, pref, shv);

        if (s1.done) {
            if (t == 0) {
                double cntd = (double)P + (double)(N - negn);
                if (cntd < 1.0) cntd = 1.0;
                sls[br] = (CE0 + CE1NN) / cntd;
                slb[br] = lb;
            }
            __syncthreads();
            continue;
        }

        unsigned sel2, tnx2;
        compute_sel2(cnt2_of(ws) + (size_t)br * 2048, false, s1.tnext, sel2, tnx2, pref, shv);

        // level-3 select on h3 (reduce REP2 inline)
        const ull* H3 = h3_of(ws, br);
        ull cev[4]; unsigned cnt[4], ssum = 0;
#pragma unroll
        for (int j = 0; j < 4; j++) {
            int i = t * 4 + j;
            ull e = 0;
#pragma unroll
            for (int r = 0; r < REP2; r++) e += H3[(size_t)i * REP2 + r];
            cev[j] = e;
            cnt[j] = (unsigned)(e >> 40);
            ssum += cnt[j];
        }
        unsigned target = tnx2;
        if (t == 0) { shv[0] = 0; shv[1] = 1; }
        __syncthreads();
        pref[t] = ssum;
        __syncthreads();
        for (int off = 1; off < 256; off <<= 1) {
            unsigned x = (t >= off) ? pref[t - off] : 0u;
            __syncthreads();
            pref[t] += x;
            __syncthreads();
        }
        unsigned tot = pref[255];
        if (target > tot) target = tot;
        unsigned before = pref[t] - ssum;
#pragma unroll
        for (int j = 0; j < 4; j++) {
            if (tot && before < target && before + cnt[j] >= target) {
                shv[0] = (unsigned)(t * 4 + j);
                shv[1] = target - before;
            }
            before += cnt[j];
        }
        __syncthreads();
        unsigned sel3 = shv[0];

        ull cei = 0;
#pragma unroll
        for (int j = 0; j < 4; j++) {
            unsigned bin = (unsigned)(t * 4 + j);
            if (bin <= sel3) cei += cev[j];
        }
        cei = wred_q(cei);
        int w = t >> 6;
        if ((t & 63) == 0) qscr[w] = cei;
        __syncthreads();
        if (t == 0) {
            ull CEI = qscr[0] + qscr[1] + qscr[2] + qscr[3];
            const ull* F = fin_of(ws, br);
            ull cl = 0; double cel = 0.0;
            for (int r = 0; r < REP2; r++) {
                cl += F[r * 2];
                cel += ((const double*)F)[r * 2 + 1];
            }
            unsigned sel12 = (s1.sel1 << 11) | sel2;
            double basec = (s1.haspos && sel12 != 0) ? (double)(N - negn) : 0.0;
            double basee = (s1.haspos && sel12 != 0) ? CE1NN : 0.0;
            double cntd = (double)P + basec + (double)cl + (double)(CEI >> 40);
            if (cntd < 1.0) cntd = 1.0;
            double ce = CE0 + basee + cel + (double)(CEI & MASK40) / (double)CE_SCALE;
            sls[br] = ce / cntd;
            slb[br] = lb;
        }
        __syncthreads();
    }

    if (t == 0) {
        out[0] = (float)(sls[0] + slb[0] + sls[1] + slb[1]);
        out[1] = (float)sls[0];
        out[2] = (float)slb[0];
        out[3] = (float)sls[1];
        out[4] = (float)slb[1];
    }
}

// ---------------- host ----------------
template <bool S>
static void run_pipeline(const float4* sc0, const float4* bb0, const float4* mk0, const float4* lb0,
                         const float4* sc1, const float4* bb1, const float4* mk1, const float4* lb1,
                         void* ws, float* out, hipStream_t stream)
{
    pass1<S><<<P1_GRID, BLK, 0, stream>>>(sc0, bb0, mk0, lb0, sc1, bb1, mk1, lb1, ws);
    refine2_k2<S><<<GRID_R, BLK, 0, stream>>>(sc0, lb0, sc1, lb1, ws);
    refine3_k2<S><<<GRID_R, BLK, 0, stream>>>(sc0, lb0, sc1, lb1, ws);
    scan_final<<<1, BLK, 0, stream>>>(ws, out);
}

extern "C" void kernel_launch(void* const* d_in, const int* in_sizes, int n_in,
                              void* d_out, int out_size, void* d_ws, size_t ws_size,
                              hipStream_t stream)
{
    (void)in_sizes; (void)n_in; (void)out_size;
    const float4* sc0 = (const float4*)d_in[0];
    const float4* bb0 = (const float4*)d_in[1];
    const float4* mk0 = (const float4*)d_in[2];
    const float4* lb0 = (const float4*)d_in[3];
    const float4* sc1 = (const float4*)d_in[4];
    const float4* bb1 = (const float4*)d_in[5];
    const float4* mk1 = (const float4*)d_in[6];
    const float4* lb1 = (const float4*)d_in[7];
    float* out = (float*)d_out;

    zero_ws_k<<<(ZERO_V4 + BLK - 1) / BLK, BLK, 0, stream>>>((uint4*)d_ws, ZERO_V4);

    if (ws_size >= WS_NEED)
        run_pipeline<true>(sc0, bb0, mk0, lb0, sc1, bb1, mk1, lb1, d_ws, out, stream);
    else
        run_pipeline<false>(sc0, bb0, mk0, lb0, sc1, bb1, mk1, lb1, d_ws, out, stream);
}